// Round 2
// baseline (155.790 us; speedup 1.0000x reference)
//
#include <hip/hip_runtime.h>
#include <math.h>

// ---------------------------------------------------------------------------
// MILossGaussian via MFMA: hist_joint(64x64) = Wx(64,P) . Wy^T(P,64) per n.
//
// R4: launch-structure round. R3 showed hist_gemm inner-loop changes are ~noise
// on the total (103.0 -> 103.6 across a 2x LDS-read restructure): the iteration
// is dominated by two 41 us harness poison fills (82 us, 82% HBM peak) plus
// launch overhead. So: collapse 3 kernel launches -> 1 kernel + 1 tiny memset.
//  - zero_ws kernel replaced by hipMemsetAsync(hist+counter, 0, 33 KB).
//  - finalize fused into hist_gemm via last-block-done pattern:
//      writers: atomicAdd(hist) -> __threadfence -> __syncthreads ->
//               t0: ACQ_REL agent fetch_add(counter)
//      last block: agent-scope atomic loads of hist (cross-XCD L2s are not
//      coherent; plain loads risk staleness) into LDS, then both n's entropies.
//  - out[0] written by plain store from the last block only (poisoned out
//    stays poisoned if the pattern breaks -> loud failure, not silent pass).
//
// Main loop is byte-identical to the verified R3 kernel (absmax 0.0):
// wave-private A/B tiles, one column per lane, full 64x64 C per wave from
// 16 ds_read_b128 + 16 MFMA per 64-elem chunk, no barriers in the loop,
// global loads prefetched one chunk ahead.
// sigma = (1/64)/2.3548 -> w = exp(-2.86131*d^2) in bin-step units; 5-bin
// window (RAD=2), center clamped to [2,61], delta from true position;
// kCoef dropped (p_joint scale-invariant); C vs C^T harmless (x<->y symmetry).
// ---------------------------------------------------------------------------

#define NBINS 64
#define LDA2 72                 // halfs per row: 144 B = 9*16B -> b128-aligned rows
#define TILEH (NBINS * LDA2)    // 4608 halfs = 9216 B per tile

typedef _Float16 half8    __attribute__((ext_vector_type(8)));
typedef float    floatx16 __attribute__((ext_vector_type(16)));

static constexpr double kSigmaD = 0.015625 / 2.3548200450309493;  // BIN_WIDTH/(2*sqrt(2*ln2))
static constexpr double kAcD    = (1.0 / (63.0 * 63.0)) / (2.0 * kSigmaD * kSigmaD);
static constexpr float  kAc     = (float)kAcD;                    // 2.86131
static constexpr float  kEps    = 1e-10f;

// block-wide (128-thread) sum + broadcast
__device__ __forceinline__ float bsum128(float v, volatile float* sm) {
#pragma unroll
    for (int off = 32; off > 0; off >>= 1) v += __shfl_down(v, off, 64);
    __syncthreads();
    if ((threadIdx.x & 63) == 0) sm[threadIdx.x >> 6] = v;
    __syncthreads();
    return sm[0] + sm[1];
}

__global__ __launch_bounds__(128, 2) void hist_gemm_kernel(
        const float* __restrict__ x, const float* __restrict__ y,
        float* __restrict__ hist, int* __restrict__ counter,
        float* __restrict__ out, int P, int elemsPerWave, int totalBlocks) {
    // per-wave private tiles: [wave][A=0/B=1][row][k]; reused as f32 scratch
    // in the epilogue (36864 B >= 32768 B needed for the full 2x64x64 hist).
    __shared__ __align__(16) _Float16 tiles[2][2][NBINS][LDA2];   // 36864 B
    __shared__ float smr[2];
    __shared__ int   sIsLast;

    const int t    = threadIdx.x;
    const int lane = t & 63;
    const int wave = t >> 6;
    const int n    = blockIdx.y;

    _Float16* __restrict__ Ax = &tiles[wave][0][0][0];
    _Float16* __restrict__ By = &tiles[wave][1][0][0];

    // zero this wave's own tiles (barrier-free: wave-private)
    {
        float4* p4 = (float4*)Ax;                      // Ax,By contiguous: 18432 B
        const int n16 = 2 * TILEH * 2 / 16;            // 1152 float4
        for (int i = lane; i < n16; i += 64) p4[i] = float4{0.f, 0.f, 0.f, 0.f};
    }

    floatx16 acc[2][2] = {};                           // full 64x64 C per wave
    const float* __restrict__ xp = x + (size_t)n * P;
    const float* __restrict__ yp = y + (size_t)n * P;

    const int waveBase = (blockIdx.x * 2 + wave) * elemsPerWave;
    int lim = P - waveBase;                            // robustness vs exact split
    if (lim > elemsPerWave) lim = elemsPerWave;
    const int nChunks = (elemsPerWave + 63) / 64;      // 14 (last chunk half-masked)

#define GLOAD(c2, ox, oy) do {                                   \
        int off_ = (c2) * 64 + lane;                             \
        int g_ = waveBase + ((off_ < lim) ? off_ : 0);           \
        g_ = min(g_, P - 1);                                     \
        ox = xp[g_]; oy = yp[g_];                                \
    } while (0)

    int pcx = 2, pcy = 2;                              // previous stamp centers (rows 0..4 start zero)
    float vx, vy;
    GLOAD(0, vx, vy);                                  // prefetch chunk 0

    for (int c = 0; c < nChunks; ++c) {
        // prefetch next chunk's element while we crunch this one
        float nvx = 0.f, nvy = 0.f;
        if (c + 1 < nChunks) GLOAD(c + 1, nvx, nvy);

        const bool valid = (c * 64 + lane) < lim;
        float wx[5], wy[5];
        int cx = 2, cy = 2;
        if (valid) {
            const float sx = vx * 63.0f;
            const float sy = vy * 63.0f;
            cx = min(max((int)(sx + 0.5f), 2), 61);
            cy = min(max((int)(sy + 0.5f), 2), 61);
            const float dx = sx - (float)cx;
            const float dy = sy - (float)cy;
#pragma unroll
            for (int k = 0; k < 5; ++k) {
                const float ddx = dx - (float)(k - 2);
                const float ddy = dy - (float)(k - 2);
                wx[k] = __expf(-kAc * ddx * ddx);
                wy[k] = __expf(-kAc * ddy * ddy);
            }
        } else {
#pragma unroll
            for (int k = 0; k < 5; ++k) { wx[k] = 0.0f; wy[k] = 0.0f; }
        }

        // un-write previous stamp, then write new one (lane owns column `lane`)
#pragma unroll
        for (int k = 0; k < 5; ++k) {
            Ax[(pcx - 2 + k) * LDA2 + lane] = (_Float16)0.0f;
            By[(pcy - 2 + k) * LDA2 + lane] = (_Float16)0.0f;
        }
#pragma unroll
        for (int k = 0; k < 5; ++k) {
            Ax[(cx - 2 + k) * LDA2 + lane] = (_Float16)wx[k];
            By[(cy - 2 + k) * LDA2 + lane] = (_Float16)wy[k];
        }
        pcx = cx; pcy = cy;

        // fragments: A[m=lane&31][k = kb*16 + 8*(lane>>5) + j]; amp 1.0:
        // each 16B row segment read exactly once, all 4 quadrants from regs.
        const int mrow = lane & 31;
        const int kq   = 8 * (lane >> 5);
        const _Float16* pa = &Ax[mrow * LDA2 + kq];
        const _Float16* pb = &By[mrow * LDA2 + kq];
#pragma unroll
        for (int kb = 0; kb < 4; ++kb) {
            const half8 a0 = *(const half8*)(pa + kb * 16);
            const half8 a1 = *(const half8*)(pa + 32 * LDA2 + kb * 16);
            const half8 b0 = *(const half8*)(pb + kb * 16);
            const half8 b1 = *(const half8*)(pb + 32 * LDA2 + kb * 16);
            acc[0][0] = __builtin_amdgcn_mfma_f32_32x32x16_f16(a0, b0, acc[0][0], 0, 0, 0);
            acc[0][1] = __builtin_amdgcn_mfma_f32_32x32x16_f16(a0, b1, acc[0][1], 0, 0, 0);
            acc[1][0] = __builtin_amdgcn_mfma_f32_32x32x16_f16(a1, b0, acc[1][0], 0, 0, 0);
            acc[1][1] = __builtin_amdgcn_mfma_f32_32x32x16_f16(a1, b1, acc[1][1], 0, 0, 0);
        }

        vx = nvx; vy = nvy;
    }
#undef GLOAD

    // epilogue: C/D layout col=lane&31, row=(r&3)+8*(r>>2)+4*(lane>>5).
    // Dump each wave's 64x64 into its own tile region, reduce across the
    // 2 waves, one atomicAdd per address per block.
    float* wsum = (float*)&tiles[wave][0][0][0];
#pragma unroll
    for (int qi = 0; qi < 2; ++qi)
#pragma unroll
        for (int qj = 0; qj < 2; ++qj)
#pragma unroll
            for (int r = 0; r < 16; ++r) {
                const int row = qi * 32 + (r & 3) + 8 * (r >> 2) + 4 * (lane >> 5);
                const int col = qj * 32 + (lane & 31);
                wsum[row * NBINS + col] = acc[qi][qj][r];
            }
    __syncthreads();

    float* __restrict__ gh = hist + (size_t)n * NBINS * NBINS;
    const float* w0 = (const float*)&tiles[0][0][0][0];
    const float* w1 = (const float*)&tiles[1][0][0][0];
    for (int i = t; i < NBINS * NBINS; i += 128) {
        atomicAdd(&gh[i], w0[i] + w1[i]);
    }

    // ---- last-block-done completion, then fused finalize -------------------
    __threadfence();                    // release this block's hist atomics
    __syncthreads();
    if (t == 0) {
        int done = __hip_atomic_fetch_add(counter, 1, __ATOMIC_ACQ_REL,
                                          __HIP_MEMORY_SCOPE_AGENT);
        sIsLast = (done == totalBlocks - 1);
    }
    __syncthreads();
    if (!sIsLast) return;

    // last block: pull full 2x64x64 hist into LDS via agent-scope loads
    // (per-XCD L2 non-coherence: plain loads could be stale).
    float* hl = (float*)&tiles[0][0][0][0];            // 32768 B of 36864
    for (int i = t; i < 2 * NBINS * NBINS; i += 128)
        hl[i] = __hip_atomic_load(&hist[i], __ATOMIC_RELAXED,
                                  __HIP_MEMORY_SCOPE_AGENT);
    __syncthreads();

    float res = 0.0f;
    for (int n2 = 0; n2 < 2; ++n2) {
        const float* h = hl + n2 * NBINS * NBINS;

        float s = 0.0f;
        for (int i = t; i < NBINS * NBINS; i += 128) s += h[i];
        const float S = bsum128(s, smr) + kEps;
        const float invS = 1.0f / S;

        float ej = 0.0f;
        for (int i = t; i < NBINS * NBINS; i += 128) {
            const float p = h[i] * invS;
            ej += p * __logf(p + kEps);
        }
        const float EJ = bsum128(ej, smr);

        float m = 0.0f;
        if (t < NBINS) {
            // row sums: rotate column start by t to avoid 64-way bank conflict
            float px = 0.0f;
            const float* rp = &h[t * NBINS];
            for (int c2 = 0; c2 < NBINS; ++c2) px += rp[(c2 + t) & 63];
            px *= invS;
            m = px * __logf(px + kEps);
        } else {
            // col sums: lanes read consecutive addresses -> conflict-free
            const int c2 = t - NBINS;
            float py = 0.0f;
            for (int b = 0; b < NBINS; ++b) py += h[b * NBINS + c2];
            py *= invS;
            m = py * __logf(py + kEps);
        }
        const float EXY = bsum128(m, smr);             // EX + EY in one pass
        res += EXY / EJ;
    }
    if (t == 0) out[0] = -0.5f * res;
}

extern "C" void kernel_launch(void* const* d_in, const int* in_sizes, int n_in,
                              void* d_out, int out_size, void* d_ws, size_t ws_size,
                              hipStream_t stream) {
    const float* x = (const float*)d_in[0];
    const float* y = (const float*)d_in[1];
    float* hist    = (float*)d_ws;                 // 2 * 64 * 64 floats = 32 KB
    int*   counter = (int*)((char*)d_ws + 2 * NBINS * NBINS * sizeof(float));
    float* out     = (float*)d_out;

    const int N = 2;
    const int P = in_sizes[0] / N;                 // 884736
    const int blocksPerN   = 512;                  // 1024 blocks total -> 4/CU
    const int elemsPerWave = P / (blocksPerN * 2); // 864 (exact)
    const int totalBlocks  = blocksPerN * N;

    // zero hist (32 KB) + counter in one async memset (graph-capturable)
    hipMemsetAsync(d_ws, 0, 2 * NBINS * NBINS * sizeof(float) + 64, stream);

    dim3 grid(blocksPerN, N);
    hist_gemm_kernel<<<grid, 128, 0, stream>>>(x, y, hist, counter, out,
                                               P, elemsPerWave, totalBlocks);
}

// Round 3
// 123.210 us; speedup vs baseline: 1.2644x; 1.2644x over previous
//
#include <hip/hip_runtime.h>
#include <math.h>

// ---------------------------------------------------------------------------
// MILossGaussian via MFMA: hist_joint(64x64) = Wx(64,P) . Wy^T(P,64) per n.
//
// R5: R4's fused single-kernel structure minus the fence catastrophe.
// R4 post-mortem: hist_gemm 100 us (vs <=41 in R3) with all pipes idle --
// __threadfence() in 2048 waves + ACQ_REL agent fetch_add compile to L2
// writeback/invalidate (buffer_wbl2/buffer_inv sc1) which serialize at the
// 8 per-XCD L2s. The fences are unnecessary: ALL cross-block data flows
// through agent-scope atomics (atomicAdd writes, atomic loads in the last
// block), which are performed at the device coherence point and bypass the
// non-coherent L2s. Ordering requirement is only "hist atomics acked before
// counter increment", and __syncthreads() already drains vmcnt(0) per wave
// before s_barrier. So: no __threadfence, RELAXED counter RMW, RELAXED
// agent reader loads. Zero cache-maintenance instructions in the kernel.
//
// Main loop byte-identical to verified R3/R4 (absmax 0.0): wave-private A/B
// tiles, one column per lane, full 64x64 C per wave from 16 ds_read_b128 +
// 16 MFMA per 64-elem chunk, barrier-free loop, global loads prefetched one
// chunk ahead. sigma = (1/64)/2.3548 -> w = exp(-2.86131*d^2) in bin-step
// units; 5-bin window, center clamped [2,61], delta from true position;
// kCoef dropped (p_joint scale-invariant); C vs C^T harmless (x<->y symm).
// ---------------------------------------------------------------------------

#define NBINS 64
#define LDA2 72                 // halfs per row: 144 B = 9*16B -> b128-aligned rows
#define TILEH (NBINS * LDA2)    // 4608 halfs = 9216 B per tile

typedef _Float16 half8    __attribute__((ext_vector_type(8)));
typedef float    floatx16 __attribute__((ext_vector_type(16)));

static constexpr double kSigmaD = 0.015625 / 2.3548200450309493;  // BIN_WIDTH/(2*sqrt(2*ln2))
static constexpr double kAcD    = (1.0 / (63.0 * 63.0)) / (2.0 * kSigmaD * kSigmaD);
static constexpr float  kAc     = (float)kAcD;                    // 2.86131
static constexpr float  kEps    = 1e-10f;

// block-wide (128-thread) sum + broadcast
__device__ __forceinline__ float bsum128(float v, volatile float* sm) {
#pragma unroll
    for (int off = 32; off > 0; off >>= 1) v += __shfl_down(v, off, 64);
    __syncthreads();
    if ((threadIdx.x & 63) == 0) sm[threadIdx.x >> 6] = v;
    __syncthreads();
    return sm[0] + sm[1];
}

__global__ __launch_bounds__(128, 2) void hist_gemm_kernel(
        const float* __restrict__ x, const float* __restrict__ y,
        float* __restrict__ hist, int* __restrict__ counter,
        float* __restrict__ out, int P, int elemsPerWave, int totalBlocks) {
    // per-wave private tiles: [wave][A=0/B=1][row][k]; reused as f32 scratch
    // in the epilogue (36864 B >= 32768 B needed for the full 2x64x64 hist).
    __shared__ __align__(16) _Float16 tiles[2][2][NBINS][LDA2];   // 36864 B
    __shared__ float smr[2];
    __shared__ int   sIsLast;

    const int t    = threadIdx.x;
    const int lane = t & 63;
    const int wave = t >> 6;
    const int n    = blockIdx.y;

    _Float16* __restrict__ Ax = &tiles[wave][0][0][0];
    _Float16* __restrict__ By = &tiles[wave][1][0][0];

    // zero this wave's own tiles (barrier-free: wave-private)
    {
        float4* p4 = (float4*)Ax;                      // Ax,By contiguous: 18432 B
        const int n16 = 2 * TILEH * 2 / 16;            // 1152 float4
        for (int i = lane; i < n16; i += 64) p4[i] = float4{0.f, 0.f, 0.f, 0.f};
    }

    floatx16 acc[2][2] = {};                           // full 64x64 C per wave
    const float* __restrict__ xp = x + (size_t)n * P;
    const float* __restrict__ yp = y + (size_t)n * P;

    const int waveBase = (blockIdx.x * 2 + wave) * elemsPerWave;
    int lim = P - waveBase;                            // robustness vs exact split
    if (lim > elemsPerWave) lim = elemsPerWave;
    const int nChunks = (elemsPerWave + 63) / 64;      // 14 (last chunk half-masked)

#define GLOAD(c2, ox, oy) do {                                   \
        int off_ = (c2) * 64 + lane;                             \
        int g_ = waveBase + ((off_ < lim) ? off_ : 0);           \
        g_ = min(g_, P - 1);                                     \
        ox = xp[g_]; oy = yp[g_];                                \
    } while (0)

    int pcx = 2, pcy = 2;                              // previous stamp centers (rows 0..4 start zero)
    float vx, vy;
    GLOAD(0, vx, vy);                                  // prefetch chunk 0

    for (int c = 0; c < nChunks; ++c) {
        // prefetch next chunk's element while we crunch this one
        float nvx = 0.f, nvy = 0.f;
        if (c + 1 < nChunks) GLOAD(c + 1, nvx, nvy);

        const bool valid = (c * 64 + lane) < lim;
        float wx[5], wy[5];
        int cx = 2, cy = 2;
        if (valid) {
            const float sx = vx * 63.0f;
            const float sy = vy * 63.0f;
            cx = min(max((int)(sx + 0.5f), 2), 61);
            cy = min(max((int)(sy + 0.5f), 2), 61);
            const float dx = sx - (float)cx;
            const float dy = sy - (float)cy;
#pragma unroll
            for (int k = 0; k < 5; ++k) {
                const float ddx = dx - (float)(k - 2);
                const float ddy = dy - (float)(k - 2);
                wx[k] = __expf(-kAc * ddx * ddx);
                wy[k] = __expf(-kAc * ddy * ddy);
            }
        } else {
#pragma unroll
            for (int k = 0; k < 5; ++k) { wx[k] = 0.0f; wy[k] = 0.0f; }
        }

        // un-write previous stamp, then write new one (lane owns column `lane`)
#pragma unroll
        for (int k = 0; k < 5; ++k) {
            Ax[(pcx - 2 + k) * LDA2 + lane] = (_Float16)0.0f;
            By[(pcy - 2 + k) * LDA2 + lane] = (_Float16)0.0f;
        }
#pragma unroll
        for (int k = 0; k < 5; ++k) {
            Ax[(cx - 2 + k) * LDA2 + lane] = (_Float16)wx[k];
            By[(cy - 2 + k) * LDA2 + lane] = (_Float16)wy[k];
        }
        pcx = cx; pcy = cy;

        // fragments: A[m=lane&31][k = kb*16 + 8*(lane>>5) + j]; amp 1.0:
        // each 16B row segment read exactly once, all 4 quadrants from regs.
        const int mrow = lane & 31;
        const int kq   = 8 * (lane >> 5);
        const _Float16* pa = &Ax[mrow * LDA2 + kq];
        const _Float16* pb = &By[mrow * LDA2 + kq];
#pragma unroll
        for (int kb = 0; kb < 4; ++kb) {
            const half8 a0 = *(const half8*)(pa + kb * 16);
            const half8 a1 = *(const half8*)(pa + 32 * LDA2 + kb * 16);
            const half8 b0 = *(const half8*)(pb + kb * 16);
            const half8 b1 = *(const half8*)(pb + 32 * LDA2 + kb * 16);
            acc[0][0] = __builtin_amdgcn_mfma_f32_32x32x16_f16(a0, b0, acc[0][0], 0, 0, 0);
            acc[0][1] = __builtin_amdgcn_mfma_f32_32x32x16_f16(a0, b1, acc[0][1], 0, 0, 0);
            acc[1][0] = __builtin_amdgcn_mfma_f32_32x32x16_f16(a1, b0, acc[1][0], 0, 0, 0);
            acc[1][1] = __builtin_amdgcn_mfma_f32_32x32x16_f16(a1, b1, acc[1][1], 0, 0, 0);
        }

        vx = nvx; vy = nvy;
    }
#undef GLOAD

    // epilogue: C/D layout col=lane&31, row=(r&3)+8*(r>>2)+4*(lane>>5).
    // Dump each wave's 64x64 into its own tile region, reduce across the
    // 2 waves, one atomicAdd per address per block.
    float* wsum = (float*)&tiles[wave][0][0][0];
#pragma unroll
    for (int qi = 0; qi < 2; ++qi)
#pragma unroll
        for (int qj = 0; qj < 2; ++qj)
#pragma unroll
            for (int r = 0; r < 16; ++r) {
                const int row = qi * 32 + (r & 3) + 8 * (r >> 2) + 4 * (lane >> 5);
                const int col = qj * 32 + (lane & 31);
                wsum[row * NBINS + col] = acc[qi][qj][r];
            }
    __syncthreads();

    float* __restrict__ gh = hist + (size_t)n * NBINS * NBINS;
    const float* w0 = (const float*)&tiles[0][0][0][0];
    const float* w1 = (const float*)&tiles[1][0][0][0];
    for (int i = t; i < NBINS * NBINS; i += 128) {
        atomicAdd(&gh[i], w0[i] + w1[i]);
    }

    // ---- last-block-done completion (fence-free), then fused finalize -----
    // __syncthreads() drains vmcnt(0) per wave before s_barrier -> every
    // block's hist atomicAdds are ACKED at the coherence point before t0
    // increments the counter. All cross-block data is atomics-only, so no
    // cache-maintenance fence (__threadfence / ACQ_REL) is needed.
    __syncthreads();
    asm volatile("" ::: "memory");      // compiler-only barrier (no codegen)
    if (t == 0) {
        asm volatile("s_waitcnt vmcnt(0)" ::: "memory");   // belt-and-braces
        int done = __hip_atomic_fetch_add(counter, 1, __ATOMIC_RELAXED,
                                          __HIP_MEMORY_SCOPE_AGENT);
        sIsLast = (done == totalBlocks - 1);
    }
    __syncthreads();
    if (!sIsLast) return;

    // last block: pull full 2x64x64 hist into LDS via agent-scope atomic
    // loads (bypass the non-coherent per-XCD L2s; no invalidate needed).
    float* hl = (float*)&tiles[0][0][0][0];            // 32768 B of 36864
    for (int i = t; i < 2 * NBINS * NBINS; i += 128)
        hl[i] = __hip_atomic_load(&hist[i], __ATOMIC_RELAXED,
                                  __HIP_MEMORY_SCOPE_AGENT);
    __syncthreads();

    float res = 0.0f;
    for (int n2 = 0; n2 < 2; ++n2) {
        const float* h = hl + n2 * NBINS * NBINS;

        float s = 0.0f;
        for (int i = t; i < NBINS * NBINS; i += 128) s += h[i];
        const float S = bsum128(s, smr) + kEps;
        const float invS = 1.0f / S;

        float ej = 0.0f;
        for (int i = t; i < NBINS * NBINS; i += 128) {
            const float p = h[i] * invS;
            ej += p * __logf(p + kEps);
        }
        const float EJ = bsum128(ej, smr);

        float m = 0.0f;
        if (t < NBINS) {
            // row sums: rotate column start by t to avoid 64-way bank conflict
            float px = 0.0f;
            const float* rp = &h[t * NBINS];
            for (int c2 = 0; c2 < NBINS; ++c2) px += rp[(c2 + t) & 63];
            px *= invS;
            m = px * __logf(px + kEps);
        } else {
            // col sums: lanes read consecutive addresses -> conflict-free
            const int c2 = t - NBINS;
            float py = 0.0f;
            for (int b = 0; b < NBINS; ++b) py += h[b * NBINS + c2];
            py *= invS;
            m = py * __logf(py + kEps);
        }
        const float EXY = bsum128(m, smr);             // EX + EY in one pass
        res += EXY / EJ;
    }
    if (t == 0) out[0] = -0.5f * res;
}

extern "C" void kernel_launch(void* const* d_in, const int* in_sizes, int n_in,
                              void* d_out, int out_size, void* d_ws, size_t ws_size,
                              hipStream_t stream) {
    const float* x = (const float*)d_in[0];
    const float* y = (const float*)d_in[1];
    float* hist    = (float*)d_ws;                 // 2 * 64 * 64 floats = 32 KB
    int*   counter = (int*)((char*)d_ws + 2 * NBINS * NBINS * sizeof(float));
    float* out     = (float*)d_out;

    const int N = 2;
    const int P = in_sizes[0] / N;                 // 884736
    const int blocksPerN   = 512;                  // 1024 blocks total -> 4/CU
    const int elemsPerWave = P / (blocksPerN * 2); // 864 (exact)
    const int totalBlocks  = blocksPerN * N;

    // zero hist (32 KB) + counter in one async memset (graph-capturable)
    hipMemsetAsync(d_ws, 0, 2 * NBINS * NBINS * sizeof(float) + 64, stream);

    dim3 grid(blocksPerN, N);
    hist_gemm_kernel<<<grid, 128, 0, stream>>>(x, y, hist, counter, out,
                                               P, elemsPerWave, totalBlocks);
}